// Round 1
// baseline (132.951 us; speedup 1.0000x reference)
//
#include <hip/hip_runtime.h>
#include <math.h>

#define BB 64
#define SQ 32
#define SD 256
#define HH 128
#define NQ (BB*SQ)   // 2048
#define ND (BB*SD)   // 16384

using short8  = __attribute__((ext_vector_type(8))) short;
using floatx4 = __attribute__((ext_vector_type(4))) float;

__device__ inline unsigned short f2bf(float x) {
  union { float f; unsigned u; } c; c.f = x;
  unsigned r = c.u + 0x7fffu + ((c.u >> 16) & 1u);  // RNE
  return (unsigned short)(r >> 16);
}

// ---------------------------------------------------------------------------
// Kernel 1: per-row inverse L2 norm for q and d; optionally stage normalized
// rows as bf16 into workspace. 8 rows per 256-thread block, 32 lanes/row.
// ---------------------------------------------------------------------------
__global__ void norm_kernel(const float* __restrict__ qe, const float* __restrict__ de,
                            float* __restrict__ inv_q, float* __restrict__ inv_d,
                            unsigned short* __restrict__ qng, unsigned short* __restrict__ dng,
                            int staged) {
  int row  = blockIdx.x * 8 + (threadIdx.x >> 5);
  int lane = threadIdx.x & 31;
  const float* src = (row < NQ) ? (qe + (size_t)row * HH) : (de + (size_t)(row - NQ) * HH);
  float4 v = ((const float4*)src)[lane];
  float ss = v.x*v.x + v.y*v.y + v.z*v.z + v.w*v.w;
#pragma unroll
  for (int off = 16; off; off >>= 1) ss += __shfl_xor(ss, off);
  float inv = 1.0f / fmaxf(sqrtf(ss), 1e-12f);
  if (lane == 0) {
    if (row < NQ) inv_q[row] = inv; else inv_d[row - NQ] = inv;
  }
  if (staged) {
    ushort4 o;
    o.x = f2bf(v.x * inv); o.y = f2bf(v.y * inv);
    o.z = f2bf(v.z * inv); o.w = f2bf(v.w * inv);
    unsigned short* dst = (row < NQ) ? (qng + (size_t)row * HH)
                                     : (dng + (size_t)(row - NQ) * HH);
    ((ushort4*)dst)[lane] = o;
  }
}

// ---------------------------------------------------------------------------
// Kernel 2: per-batch avg pairwise similarity.
//   avg[b] = (||sum_s n_s||^2 - sum_s ||n_s||^2) / (S*(S-1))
// blocks 0..63 -> q batches, 64..127 -> d batches. 256 thr: 2 row-groups x 128 h.
// ---------------------------------------------------------------------------
__global__ void batch_stats_kernel(const float* __restrict__ qe, const float* __restrict__ de,
                                   const float* __restrict__ inv_q, const float* __restrict__ inv_d,
                                   float* __restrict__ avgq, float* __restrict__ avgd) {
  __shared__ float l1[256];
  __shared__ float red[4];
  const int bid = blockIdx.x, tid = threadIdx.x;
  const int g = tid >> 7, h = tid & 127;
  const float* src; const float* inv; int S; float* outp;
  if (bid < BB) { src = qe + (size_t)bid * SQ * HH; inv = inv_q + bid * SQ; S = SQ; outp = avgq + bid; }
  else { src = de + (size_t)(bid - BB) * SD * HH; inv = inv_d + (bid - BB) * SD; S = SD; outp = avgd + (bid - BB); }
  float a1 = 0.f, a2 = 0.f;
  for (int s = g; s < S; s += 2) {
    float v = src[s * HH + h] * inv[s];
    a1 += v; a2 += v * v;
  }
  l1[tid] = a1;
  __syncthreads();
  float z = -a2;
  if (tid < 128) { float t = l1[tid] + l1[tid + 128]; z += t * t; }
#pragma unroll
  for (int off = 32; off; off >>= 1) z += __shfl_xor(z, off);
  if ((tid & 63) == 0) red[tid >> 6] = z;
  __syncthreads();
  if (tid == 0) {
    float num = red[0] + red[1] + red[2] + red[3];
    *outp = num / (float)(S * (S - 1));
  }
}

// ---------------------------------------------------------------------------
// Kernel 3: scores[a,b] = max_{s,t} (qn[a,s]·dn[b,t]) * qm[a,s] * dm[b,t]
// One block per (a,b). 256 thr = 4 waves. LDS: 32x136 + 256x136 bf16 (pad +8
// -> 2-way bank alias on ds_read_b128, free). Wave w owns 64 N-columns:
// 2 (M) x 4 (N) 16x16 tiles, K=128 in 4 MFMA steps.
// ---------------------------------------------------------------------------
template<int STAGED>
__global__ __launch_bounds__(256, 2) void scores_kernel(
    const float* __restrict__ qe, const float* __restrict__ de,
    const int* __restrict__ qmask, const int* __restrict__ dmask,
    const float* __restrict__ inv_q, const float* __restrict__ inv_d,
    const unsigned short* __restrict__ qng, const unsigned short* __restrict__ dng,
    float* __restrict__ scores) {
  __shared__ __align__(16) unsigned short qs[SQ][HH + 8];
  __shared__ __align__(16) unsigned short dt[SD][HH + 8];
  __shared__ float qmf[SQ];
  __shared__ float dmf[SD];
  __shared__ float wred[4];
  const int tid = threadIdx.x;
  const int bb = blockIdx.x, aa = blockIdx.y;

  if (tid < SQ) qmf[tid] = (float)qmask[aa * SQ + tid];
  dmf[tid] = (float)dmask[bb * SD + tid];

  if (STAGED) {
#pragma unroll
    for (int i = 0; i < 2; i++) {      // q tile: 512 x 16B
      int idx = i * 256 + tid; int row = idx >> 4, c = idx & 15;
      uint4 v = ((const uint4*)(qng + (size_t)(aa * SQ + row) * HH))[c];
      *(uint4*)&qs[row][c * 8] = v;
    }
#pragma unroll
    for (int i = 0; i < 16; i++) {     // d tile: 4096 x 16B
      int idx = i * 256 + tid; int row = idx >> 4, c = idx & 15;
      uint4 v = ((const uint4*)(dng + (size_t)(bb * SD + row) * HH))[c];
      *(uint4*)&dt[row][c * 8] = v;
    }
  } else {
#pragma unroll
    for (int i = 0; i < 4; i++) {      // q tile fp32 -> bf16
      int idx = i * 256 + tid; int row = idx >> 5, c = idx & 31;
      float4 v = ((const float4*)(qe + (size_t)(aa * SQ + row) * HH))[c];
      float s = inv_q[aa * SQ + row];
      ushort4 o; o.x = f2bf(v.x * s); o.y = f2bf(v.y * s); o.z = f2bf(v.z * s); o.w = f2bf(v.w * s);
      *(ushort4*)&qs[row][c * 4] = o;
    }
#pragma unroll
    for (int i = 0; i < 32; i++) {     // d tile fp32 -> bf16
      int idx = i * 256 + tid; int row = idx >> 5, c = idx & 31;
      float4 v = ((const float4*)(de + (size_t)(bb * SD + row) * HH))[c];
      float s = inv_d[bb * SD + row];
      ushort4 o; o.x = f2bf(v.x * s); o.y = f2bf(v.y * s); o.z = f2bf(v.z * s); o.w = f2bf(v.w * s);
      *(ushort4*)&dt[row][c * 4] = o;
    }
  }
  __syncthreads();

  const int wave = tid >> 6, lane = tid & 63;
  const int quad = lane >> 4, l16 = lane & 15;
  const floatx4 zero = {0.f, 0.f, 0.f, 0.f};
  floatx4 acc[2][4];
#pragma unroll
  for (int mi = 0; mi < 2; mi++)
#pragma unroll
    for (int ni = 0; ni < 4; ni++) acc[mi][ni] = zero;

#pragma unroll
  for (int k0 = 0; k0 < HH; k0 += 32) {
    short8 af[2], bf[4];
#pragma unroll
    for (int mi = 0; mi < 2; mi++)
      af[mi] = *(const short8*)&qs[mi * 16 + l16][k0 + quad * 8];
#pragma unroll
    for (int ni = 0; ni < 4; ni++)
      bf[ni] = *(const short8*)&dt[wave * 64 + ni * 16 + l16][k0 + quad * 8];
#pragma unroll
    for (int mi = 0; mi < 2; mi++)
#pragma unroll
      for (int ni = 0; ni < 4; ni++)
        acc[mi][ni] = __builtin_amdgcn_mfma_f32_16x16x32_bf16(af[mi], bf[ni], acc[mi][ni], 0, 0, 0);
  }

  // masked max. C/D layout: col = lane&15 (t), row = quad*4 + reg (s).
  float dmv[4];
#pragma unroll
  for (int ni = 0; ni < 4; ni++) dmv[ni] = dmf[wave * 64 + ni * 16 + l16];
  float m = -1e30f;
#pragma unroll
  for (int mi = 0; mi < 2; mi++)
#pragma unroll
    for (int r = 0; r < 4; r++) {
      float qv = qmf[mi * 16 + quad * 4 + r];
#pragma unroll
      for (int ni = 0; ni < 4; ni++)
        m = fmaxf(m, acc[mi][ni][r] * qv * dmv[ni]);
    }
#pragma unroll
  for (int off = 32; off; off >>= 1) m = fmaxf(m, __shfl_xor(m, off));
  if (lane == 0) wred[wave] = m;
  __syncthreads();
  if (tid == 0)
    scores[aa * BB + bb] = fmaxf(fmaxf(wred[0], wred[1]), fmaxf(wred[2], wred[3]));
}

// ---------------------------------------------------------------------------
// Kernel 4: loss = mean_a(lse_a - diag_a) + mean(avgq) + mean(avgd)
// ---------------------------------------------------------------------------
__global__ void final_kernel(const float* __restrict__ scores,
                             const float* __restrict__ avgq, const float* __restrict__ avgd,
                             float* __restrict__ out) {
  int a = threadIdx.x;  // 0..63, one wave
  float mx = -1e30f;
  for (int b = 0; b < BB; b++) mx = fmaxf(mx, scores[a * BB + b]);
  float sum = 0.f;
  for (int b = 0; b < BB; b++) sum += expf(scores[a * BB + b] - mx);
  float v = logf(sum) + mx - scores[a * BB + a] + avgq[a] + avgd[a];
#pragma unroll
  for (int off = 32; off; off >>= 1) v += __shfl_xor(v, off);
  if (a == 0) out[0] = v * (1.0f / 64.0f);
}

// ---------------------------------------------------------------------------
extern "C" void kernel_launch(void* const* d_in, const int* in_sizes, int n_in,
                              void* d_out, int out_size, void* d_ws, size_t ws_size,
                              hipStream_t stream) {
  const float* qe   = (const float*)d_in[0];
  const float* de   = (const float*)d_in[1];
  const int* qmask  = (const int*)d_in[2];
  const int* dmask  = (const int*)d_in[3];
  float* out = (float*)d_out;
  char* ws = (char*)d_ws;

  float* inv_q  = (float*)(ws);                 // 2048 f  ->  8192 B
  float* inv_d  = (float*)(ws + 8192);          // 16384 f -> 65536 B
  float* scores = (float*)(ws + 73728);         // 4096 f  -> 16384 B
  float* avgq   = (float*)(ws + 90112);         // 64 f
  float* avgd   = (float*)(ws + 90368);         // 64 f
  unsigned short* qng = (unsigned short*)(ws + 98304);           // 2048*128 bf16
  unsigned short* dng = (unsigned short*)(ws + 98304 + 524288);  // 16384*128 bf16
  const size_t need_staged = 98304 + 524288 + 4194304;
  int staged = (ws_size >= need_staged) ? 1 : 0;   // constant per deployment: graph-safe

  norm_kernel<<<(NQ + ND) / 8, 256, 0, stream>>>(qe, de, inv_q, inv_d, qng, dng, staged);
  batch_stats_kernel<<<2 * BB, 256, 0, stream>>>(qe, de, inv_q, inv_d, avgq, avgd);
  if (staged)
    scores_kernel<1><<<dim3(BB, BB), 256, 0, stream>>>(qe, de, qmask, dmask, inv_q, inv_d, qng, dng, scores);
  else
    scores_kernel<0><<<dim3(BB, BB), 256, 0, stream>>>(qe, de, qmask, dmask, inv_q, inv_d, qng, dng, scores);
  final_kernel<<<1, 64, 0, stream>>>(scores, avgq, avgd, out);
}

// Round 3
// 118.858 us; speedup vs baseline: 1.1186x; 1.1186x over previous
//
#include <hip/hip_runtime.h>
#include <math.h>

#define BB 64
#define SQ 32
#define SD 256
#define HH 128
#define NQ (BB*SQ)   // 2048
#define ND (BB*SD)   // 16384
#define AG 8         // a's per scores block

using short8  = __attribute__((ext_vector_type(8))) short;
using floatx4 = __attribute__((ext_vector_type(4))) float;

__device__ inline unsigned short f2bf(float x) {
  union { float f; unsigned u; } c; c.f = x;
  unsigned r = c.u + 0x7fffu + ((c.u >> 16) & 1u);  // RNE
  return (unsigned short)(r >> 16);
}

// ---------------------------------------------------------------------------
// Kernel 1: per-row inverse L2 norm for q and d; stage MASK-BAKED normalized
// rows as bf16 (qng = qm*q/||q||, dng = dm*d/||d||). 8 rows/block, 32 lanes/row.
// inv_q/inv_d stay unmasked (batch_stats uses raw normalized values).
// ---------------------------------------------------------------------------
__global__ void norm_kernel(const float* __restrict__ qe, const float* __restrict__ de,
                            const int* __restrict__ qmask, const int* __restrict__ dmask,
                            float* __restrict__ inv_q, float* __restrict__ inv_d,
                            unsigned short* __restrict__ qng, unsigned short* __restrict__ dng) {
  int row  = blockIdx.x * 8 + (threadIdx.x >> 5);
  int lane = threadIdx.x & 31;
  const float* src = (row < NQ) ? (qe + (size_t)row * HH) : (de + (size_t)(row - NQ) * HH);
  float4 v = ((const float4*)src)[lane];
  float ss = v.x*v.x + v.y*v.y + v.z*v.z + v.w*v.w;
#pragma unroll
  for (int off = 16; off; off >>= 1) ss += __shfl_xor(ss, off);
  float inv = 1.0f / fmaxf(sqrtf(ss), 1e-12f);
  if (lane == 0) {
    if (row < NQ) inv_q[row] = inv; else inv_d[row - NQ] = inv;
  }
  float mfac = (row < NQ) ? (float)qmask[row] : (float)dmask[row - NQ];
  float s = inv * mfac;
  ushort4 o;
  o.x = f2bf(v.x * s); o.y = f2bf(v.y * s);
  o.z = f2bf(v.z * s); o.w = f2bf(v.w * s);
  unsigned short* dst = (row < NQ) ? (qng + (size_t)row * HH)
                                   : (dng + (size_t)(row - NQ) * HH);
  ((ushort4*)dst)[lane] = o;
}

// ---------------------------------------------------------------------------
// Kernel 2: per-batch avg pairwise similarity (UNmasked normalized values).
//   avg[b] = (||sum_s n_s||^2 - sum_s ||n_s||^2) / (S*(S-1))
// ---------------------------------------------------------------------------
__global__ void batch_stats_kernel(const float* __restrict__ qe, const float* __restrict__ de,
                                   const float* __restrict__ inv_q, const float* __restrict__ inv_d,
                                   float* __restrict__ avgq, float* __restrict__ avgd) {
  __shared__ float l1[256];
  __shared__ float red[4];
  const int bid = blockIdx.x, tid = threadIdx.x;
  const int g = tid >> 7, h = tid & 127;
  const float* src; const float* inv; int S; float* outp;
  if (bid < BB) { src = qe + (size_t)bid * SQ * HH; inv = inv_q + bid * SQ; S = SQ; outp = avgq + bid; }
  else { src = de + (size_t)(bid - BB) * SD * HH; inv = inv_d + (bid - BB) * SD; S = SD; outp = avgd + (bid - BB); }
  float a1 = 0.f, a2 = 0.f;
  for (int s = g; s < S; s += 2) {
    float v = src[s * HH + h] * inv[s];
    a1 += v; a2 += v * v;
  }
  l1[tid] = a1;
  __syncthreads();
  float z = -a2;
  if (tid < 128) { float t = l1[tid] + l1[tid + 128]; z += t * t; }
#pragma unroll
  for (int off = 32; off; off >>= 1) z += __shfl_xor(z, off);
  if ((tid & 63) == 0) red[tid >> 6] = z;
  __syncthreads();
  if (tid == 0) {
    float num = red[0] + red[1] + red[2] + red[3];
    *outp = num / (float)(S * (S - 1));
  }
}

// ---------------------------------------------------------------------------
// Kernel 3 v2b: scores[a,b] = max_{s,t} qng[a,s]·dng[b,t]  (masks pre-baked).
// Grid (BB, BB/AG) = (64,8) = 512 blocks, 2 blocks/CU (LDS 68KB).
// Block: d-tile (256x128 bf16) in LDS shared by 4 waves; each wave holds its
// 64 q-rows (2 a's) as resident A-fragments in VGPRs. N processed in 4 chunks
// of 64 with acc[4][4]; max folds per chunk. Each wave sees all t for its 2
// a's -> writes 2 scores directly, no cross-wave reduce.
// FIX vs v2: d-tile staging index split is row = idx>>4, c = idx&15
// (256 rows x 16 chunks of 16B). v2's >>3/&7 wrote rows 256..511 OOB and
// left columns 64..127 uninitialized -> NaN.
// ---------------------------------------------------------------------------
__global__ __launch_bounds__(256, 2) void scores_kernel(
    const unsigned short* __restrict__ qng, const unsigned short* __restrict__ dng,
    float* __restrict__ scores) {
  __shared__ __align__(16) unsigned short dt[SD][HH + 8];
  const int tid = threadIdx.x;
  const int bb = blockIdx.x;
  const int m0 = blockIdx.y * AG * SQ;         // 256 q-rows per block
  const int wave = tid >> 6, lane = tid & 63;
  const int quad = lane >> 4, l16 = lane & 15;

  // stage d tile: 4096 chunks x 16B, fully coalesced (1KB per wave-instr).
#pragma unroll
  for (int i = 0; i < 16; i++) {
    int idx = i * 256 + tid;
    int row = idx >> 4, c = idx & 15;
    uint4 v = ((const uint4*)(dng + (size_t)(bb * SD + row) * HH))[c];
    *(uint4*)&dt[row][c * 8] = v;
  }

  // A fragments: wave's 64 M-rows, full K=128. 16 x short8 = 64 VGPRs.
  short8 af[4][4];
  const unsigned short* qbase = qng + (size_t)(m0 + wave * 64 + l16) * HH + quad * 8;
#pragma unroll
  for (int mi = 0; mi < 4; mi++)
#pragma unroll
    for (int kc = 0; kc < 4; kc++)
      af[mi][kc] = *(const short8*)(qbase + mi * 16 * HH + kc * 32);

  __syncthreads();

  float m0v = -1e30f, m1v = -1e30f;   // per-a maxima (a = blockIdx.y*AG + wave*2 + {0,1})
  const floatx4 zero = {0.f, 0.f, 0.f, 0.f};

#pragma unroll
  for (int nc = 0; nc < 4; nc++) {
    floatx4 acc[4][4];
#pragma unroll
    for (int mi = 0; mi < 4; mi++)
#pragma unroll
      for (int ni = 0; ni < 4; ni++) acc[mi][ni] = zero;
#pragma unroll
    for (int kc = 0; kc < 4; kc++) {
      short8 bf[4];
#pragma unroll
      for (int ni = 0; ni < 4; ni++)
        bf[ni] = *(const short8*)&dt[nc * 64 + ni * 16 + l16][kc * 32 + quad * 8];
#pragma unroll
      for (int mi = 0; mi < 4; mi++)
#pragma unroll
        for (int ni = 0; ni < 4; ni++)
          acc[mi][ni] = __builtin_amdgcn_mfma_f32_16x16x32_bf16(af[mi][kc], bf[ni], acc[mi][ni], 0, 0, 0);
    }
    // plain max (masks baked into operands; masked-out entries are exactly 0,
    // matching reference's x*qm*dm before max)
#pragma unroll
    for (int mi = 0; mi < 4; mi++) {
      float mm = -1e30f;
#pragma unroll
      for (int ni = 0; ni < 4; ni++)
#pragma unroll
        for (int r = 0; r < 4; r++) mm = fmaxf(mm, acc[mi][ni][r]);
      if (mi < 2) m0v = fmaxf(m0v, mm); else m1v = fmaxf(m1v, mm);
    }
  }
#pragma unroll
  for (int off = 32; off; off >>= 1) {
    m0v = fmaxf(m0v, __shfl_xor(m0v, off));
    m1v = fmaxf(m1v, __shfl_xor(m1v, off));
  }
  if (lane == 0) {
    int a = blockIdx.y * AG + wave * 2;
    scores[(size_t)a * BB + bb]       = m0v;
    scores[(size_t)(a + 1) * BB + bb] = m1v;
  }
}

// ---------------------------------------------------------------------------
// Kernel 4: loss = mean_a(lse_a - diag_a) + mean(avgq) + mean(avgd)
// ---------------------------------------------------------------------------
__global__ void final_kernel(const float* __restrict__ scores,
                             const float* __restrict__ avgq, const float* __restrict__ avgd,
                             float* __restrict__ out) {
  int a = threadIdx.x;  // 0..63, one wave
  float row[BB];
  const float4* p = (const float4*)(scores + (size_t)a * BB);
  float mx = -1e30f;
#pragma unroll
  for (int i = 0; i < BB / 4; i++) {
    float4 v = p[i];
    row[i*4+0] = v.x; row[i*4+1] = v.y; row[i*4+2] = v.z; row[i*4+3] = v.w;
    mx = fmaxf(mx, fmaxf(fmaxf(v.x, v.y), fmaxf(v.z, v.w)));
  }
  float sum = 0.f;
#pragma unroll
  for (int b = 0; b < BB; b++) sum += expf(row[b] - mx);
  float v = logf(sum) + mx - row[a] + avgq[a] + avgd[a];
#pragma unroll
  for (int off = 32; off; off >>= 1) v += __shfl_xor(v, off);
  if (a == 0) out[0] = v * (1.0f / 64.0f);
}

// ---------------------------------------------------------------------------
extern "C" void kernel_launch(void* const* d_in, const int* in_sizes, int n_in,
                              void* d_out, int out_size, void* d_ws, size_t ws_size,
                              hipStream_t stream) {
  const float* qe   = (const float*)d_in[0];
  const float* de   = (const float*)d_in[1];
  const int* qmask  = (const int*)d_in[2];
  const int* dmask  = (const int*)d_in[3];
  float* out = (float*)d_out;
  char* ws = (char*)d_ws;

  float* inv_q  = (float*)(ws);                 // 2048 f
  float* inv_d  = (float*)(ws + 8192);          // 16384 f
  float* scores = (float*)(ws + 73728);         // 4096 f
  float* avgq   = (float*)(ws + 90112);         // 64 f
  float* avgd   = (float*)(ws + 90368);         // 64 f
  unsigned short* qng = (unsigned short*)(ws + 98304);           // 2048*128 bf16 (mask-baked)
  unsigned short* dng = (unsigned short*)(ws + 98304 + 524288);  // 16384*128 bf16 (mask-baked)

  norm_kernel<<<(NQ + ND) / 8, 256, 0, stream>>>(qe, de, qmask, dmask, inv_q, inv_d, qng, dng);
  batch_stats_kernel<<<2 * BB, 256, 0, stream>>>(qe, de, inv_q, inv_d, avgq, avgd);
  scores_kernel<<<dim3(BB, BB / AG), 256, 0, stream>>>(qng, dng, scores);
  final_kernel<<<1, 64, 0, stream>>>(scores, avgq, avgd, out);
}

// Round 4
// 100.796 us; speedup vs baseline: 1.3190x; 1.1792x over previous
//
#include <hip/hip_runtime.h>
#include <math.h>

#define BB 64
#define SQ 32
#define SD 256
#define HH 128
#define NQ (BB*SQ)   // 2048
#define ND (BB*SD)   // 16384
#define AG 8         // a's per scores block

using short8  = __attribute__((ext_vector_type(8))) short;
using floatx4 = __attribute__((ext_vector_type(4))) float;

__device__ inline unsigned short f2bf(float x) {
  union { float f; unsigned u; } c; c.f = x;
  unsigned r = c.u + 0x7fffu + ((c.u >> 16) & 1u);  // RNE
  return (unsigned short)(r >> 16);
}

// ---------------------------------------------------------------------------
// Kernel 1 (fused): per batch sample, in ONE pass over the fp32 input:
//   - per-row inv L2 norm
//   - stage mask-baked normalized bf16 rows (qng = qm*q/||q||, dng likewise)
//   - avg pairwise similarity: (||sum_s n_s||^2 - sum_s ||n_s||^2) / (S(S-1))
// Grid: 128 blocks (0..63 q batches, 64..127 d batches), 256 threads =
// 8 row-groups x 32 lanes (float4/lane covers H=128).
// ---------------------------------------------------------------------------
__global__ __launch_bounds__(256) void prep_kernel(
    const float* __restrict__ qe, const float* __restrict__ de,
    const int* __restrict__ qmask, const int* __restrict__ dmask,
    unsigned short* __restrict__ qng, unsigned short* __restrict__ dng,
    float* __restrict__ avgq, float* __restrict__ avgd) {
  __shared__ float colsum[8 * 128];   // [group][col]
  __shared__ float red[4];
  const int bid = blockIdx.x, tid = threadIdx.x;
  const int g = tid >> 5, c = tid & 31;

  const float* src; const int* msk; unsigned short* dst; int S; float* outp;
  if (bid < BB) {
    src = qe + (size_t)bid * SQ * HH; msk = qmask + bid * SQ;
    dst = qng + (size_t)bid * SQ * HH; S = SQ; outp = avgq + bid;
  } else {
    int b = bid - BB;
    src = de + (size_t)b * SD * HH; msk = dmask + b * SD;
    dst = dng + (size_t)b * SD * HH; S = SD; outp = avgd + b;
  }

  float cs0 = 0.f, cs1 = 0.f, cs2 = 0.f, cs3 = 0.f;  // per-col partial sums
  float a2 = 0.f;                                    // partial sum ||n_s||^2
  for (int row = g; row < S; row += 8) {
    float4 v = ((const float4*)(src + (size_t)row * HH))[c];
    float ss = v.x*v.x + v.y*v.y + v.z*v.z + v.w*v.w;
#pragma unroll
    for (int off = 16; off; off >>= 1) ss += __shfl_xor(ss, off);  // 32-lane group
    float inv = 1.0f / fmaxf(sqrtf(ss), 1e-12f);
    float nx = v.x * inv, ny = v.y * inv, nz = v.z * inv, nw = v.w * inv;
    cs0 += nx; cs1 += ny; cs2 += nz; cs3 += nw;
    a2 += nx*nx + ny*ny + nz*nz + nw*nw;
    float m = (float)msk[row] * inv;
    ushort4 o;
    o.x = f2bf(v.x * m); o.y = f2bf(v.y * m);
    o.z = f2bf(v.z * m); o.w = f2bf(v.w * m);
    ((ushort4*)(dst + (size_t)row * HH))[c] = o;
  }
  // store col partials: contiguous float4 per lane -> conflict-free b128
  *(float4*)&colsum[g * 128 + c * 4] = make_float4(cs0, cs1, cs2, cs3);
  __syncthreads();

  float z = -a2;
  if (tid < 128) {
    float s = 0.f;
#pragma unroll
    for (int gg = 0; gg < 8; gg++) s += colsum[gg * 128 + tid];
    z += s * s;
  }
#pragma unroll
  for (int off = 32; off; off >>= 1) z += __shfl_xor(z, off);
  if ((tid & 63) == 0) red[tid >> 6] = z;
  __syncthreads();
  if (tid == 0) {
    float num = red[0] + red[1] + red[2] + red[3];
    *outp = num / (float)(S * (S - 1));
  }
}

// ---------------------------------------------------------------------------
// Kernel 2: scores[a,b] = max_{s,t} qng[a,s]·dng[b,t]  (masks pre-baked).
// Grid (BB, BB/AG) = (64,8) = 512 blocks, 2 blocks/CU (LDS 68KB).
// d-tile (256x128 bf16) in LDS shared by 4 waves; each wave holds its 64
// q-rows (2 a's) as resident A-fragments in VGPRs. N in 4 chunks of 64,
// acc[4][4]; max folds per chunk; each wave writes its 2 scores directly.
// ---------------------------------------------------------------------------
__global__ __launch_bounds__(256, 2) void scores_kernel(
    const unsigned short* __restrict__ qng, const unsigned short* __restrict__ dng,
    float* __restrict__ scores) {
  __shared__ __align__(16) unsigned short dt[SD][HH + 8];
  const int tid = threadIdx.x;
  const int bb = blockIdx.x;
  const int m0 = blockIdx.y * AG * SQ;         // 256 q-rows per block
  const int wave = tid >> 6, lane = tid & 63;
  const int quad = lane >> 4, l16 = lane & 15;

  // stage d tile: 4096 chunks x 16B, fully coalesced (1KB per wave-instr).
#pragma unroll
  for (int i = 0; i < 16; i++) {
    int idx = i * 256 + tid;
    int row = idx >> 4, c = idx & 15;
    uint4 v = ((const uint4*)(dng + (size_t)(bb * SD + row) * HH))[c];
    *(uint4*)&dt[row][c * 8] = v;
  }

  // A fragments: wave's 64 M-rows, full K=128. 16 x short8 = 64 VGPRs.
  short8 af[4][4];
  const unsigned short* qbase = qng + (size_t)(m0 + wave * 64 + l16) * HH + quad * 8;
#pragma unroll
  for (int mi = 0; mi < 4; mi++)
#pragma unroll
    for (int kc = 0; kc < 4; kc++)
      af[mi][kc] = *(const short8*)(qbase + mi * 16 * HH + kc * 32);

  __syncthreads();

  float m0v = -1e30f, m1v = -1e30f;   // per-a maxima (a = blockIdx.y*AG + wave*2 + {0,1})
  const floatx4 zero = {0.f, 0.f, 0.f, 0.f};

#pragma unroll
  for (int nc = 0; nc < 4; nc++) {
    floatx4 acc[4][4];
#pragma unroll
    for (int mi = 0; mi < 4; mi++)
#pragma unroll
      for (int ni = 0; ni < 4; ni++) acc[mi][ni] = zero;
#pragma unroll
    for (int kc = 0; kc < 4; kc++) {
      short8 bf[4];
#pragma unroll
      for (int ni = 0; ni < 4; ni++)
        bf[ni] = *(const short8*)&dt[nc * 64 + ni * 16 + l16][kc * 32 + quad * 8];
#pragma unroll
      for (int mi = 0; mi < 4; mi++)
#pragma unroll
        for (int ni = 0; ni < 4; ni++)
          acc[mi][ni] = __builtin_amdgcn_mfma_f32_16x16x32_bf16(af[mi][kc], bf[ni], acc[mi][ni], 0, 0, 0);
    }
#pragma unroll
    for (int mi = 0; mi < 4; mi++) {
      float mm = -1e30f;
#pragma unroll
      for (int ni = 0; ni < 4; ni++)
#pragma unroll
        for (int r = 0; r < 4; r++) mm = fmaxf(mm, acc[mi][ni][r]);
      if (mi < 2) m0v = fmaxf(m0v, mm); else m1v = fmaxf(m1v, mm);
    }
  }
#pragma unroll
  for (int off = 32; off; off >>= 1) {
    m0v = fmaxf(m0v, __shfl_xor(m0v, off));
    m1v = fmaxf(m1v, __shfl_xor(m1v, off));
  }
  if (lane == 0) {
    int a = blockIdx.y * AG + wave * 2;
    scores[(size_t)a * BB + bb]       = m0v;
    scores[(size_t)(a + 1) * BB + bb] = m1v;
  }
}

// ---------------------------------------------------------------------------
// Kernel 3: loss = mean_a(lse_a - diag_a) + mean(avgq) + mean(avgd)
// ---------------------------------------------------------------------------
__global__ void final_kernel(const float* __restrict__ scores,
                             const float* __restrict__ avgq, const float* __restrict__ avgd,
                             float* __restrict__ out) {
  int a = threadIdx.x;  // 0..63, one wave
  float row[BB];
  const float4* p = (const float4*)(scores + (size_t)a * BB);
  float mx = -1e30f;
#pragma unroll
  for (int i = 0; i < BB / 4; i++) {
    float4 v = p[i];
    row[i*4+0] = v.x; row[i*4+1] = v.y; row[i*4+2] = v.z; row[i*4+3] = v.w;
    mx = fmaxf(mx, fmaxf(fmaxf(v.x, v.y), fmaxf(v.z, v.w)));
  }
  float sum = 0.f;
#pragma unroll
  for (int b = 0; b < BB; b++) sum += expf(row[b] - mx);
  float v = logf(sum) + mx - row[a] + avgq[a] + avgd[a];
#pragma unroll
  for (int off = 32; off; off >>= 1) v += __shfl_xor(v, off);
  if (a == 0) out[0] = v * (1.0f / 64.0f);
}

// ---------------------------------------------------------------------------
extern "C" void kernel_launch(void* const* d_in, const int* in_sizes, int n_in,
                              void* d_out, int out_size, void* d_ws, size_t ws_size,
                              hipStream_t stream) {
  const float* qe   = (const float*)d_in[0];
  const float* de   = (const float*)d_in[1];
  const int* qmask  = (const int*)d_in[2];
  const int* dmask  = (const int*)d_in[3];
  float* out = (float*)d_out;
  char* ws = (char*)d_ws;

  float* scores = (float*)(ws);                 // 4096 f
  float* avgq   = (float*)(ws + 16384);         // 64 f
  float* avgd   = (float*)(ws + 16640);         // 64 f
  unsigned short* qng = (unsigned short*)(ws + 32768);           // 2048*128 bf16 (mask-baked)
  unsigned short* dng = (unsigned short*)(ws + 32768 + 524288);  // 16384*128 bf16 (mask-baked)

  prep_kernel<<<2 * BB, 256, 0, stream>>>(qe, de, qmask, dmask, qng, dng, avgq, avgd);
  scores_kernel<<<dim3(BB, BB / AG), 256, 0, stream>>>(qng, dng, scores);
  final_kernel<<<1, 64, 0, stream>>>(scores, avgq, avgd, out);
}